// Round 5
// baseline (239.219 us; speedup 1.0000x reference)
//
#include <hip/hip_runtime.h>

// Two threads per 3-qubit state. Thread u: state s = u>>1, half h = u&1,
// holding amps 4h..4h+3 (amp index = 4*q0+2*q1+q2, so h == q0).
// Fused M(q) = RX(theta_q)*H per qubit (gates on distinct qubits commute):
//   M = k*[[c-is, c+is],[c-is, -(c+is)]], k=1/sqrt(2)
//   => a' = p*a + q*b ; b' = p*a - q*b, p=k(c-is), q=k(c+is).
// q0 couples the adjacent-lane pair via __shfl_xor(.,1); q1 pairs (j,j+2)
// locally; CNOT (flip q2 when q0==1) is an index swap folded into the store.
//
// Persistent grid-stride pipeline (copy-ubench shape): 2048 long-lived
// blocks, 8 iterations each, next iteration's loads issued before current
// compute (1-deep SW pipeline), double-buffered LDS store-transpose (one
// barrier/iter), NONTEMPORAL stores so the write stream doesn't evict the
// input from L3 (round-3 FETCH=66MB of 134MB input = self-eviction).

// Native clang vector type for nontemporal builtins (HIP_vector_type is a
// struct and is rejected by __builtin_nontemporal_store).
typedef float float4_n __attribute__((ext_vector_type(4)));

__global__ __launch_bounds__(256) void circuit_kernel(
    const float4* __restrict__ xr4,
    const float4* __restrict__ xi4,
    const float* __restrict__ theta,
    float4* __restrict__ o4,
    int N,        // N = 2*B half-states
    int niters)   // ceil(N / (gridDim*blockDim))
{
    __shared__ float4 buf[2][512];
    const int tid = threadIdx.x;
    const int stride = gridDim.x * blockDim.x;
    const int h = tid & 1;  // stride is even -> u parity == tid parity
    const float k = 0.70710678118654752440f;

    float c0, s0, c1, s1;
    __sincosf(theta[0] * 0.5f, &s0, &c0);
    __sincosf(theta[1] * 0.5f, &s1, &c1);
    const float mr  = k * c0;
    const float mi  = h ? (k * s0) : (-k * s0);
    const float p1r = k * c1, p1i = -k * s1;
    const float q1r = k * c1, q1i = k * s1;

    int u = blockIdx.x * blockDim.x + tid;
    float4 fr = make_float4(0.f, 0.f, 0.f, 0.f), fi = fr;
    if (u < N) { fr = xr4[u]; fi = xi4[u]; }
    int par = 0;

    for (int it = 0; it < niters; ++it) {
        // ---- prefetch next iteration's loads (stay in flight across compute)
        const int un = u + stride;
        float4 frn = make_float4(0.f, 0.f, 0.f, 0.f), fin = frn;
        if (it + 1 < niters && un < N) { frn = xr4[un]; fin = xi4[un]; }

        // ---- fused H+RX on qubit 0 (couples adjacent-lane pair)
        float ar[4] = {fr.x, fr.y, fr.z, fr.w};
        float ai[4] = {fi.x, fi.y, fi.z, fi.w};
        float lr[4], li[4], pr[4], pi[4];
#pragma unroll
        for (int j = 0; j < 4; ++j) {
            lr[j] = mr * ar[j] - mi * ai[j];
            li[j] = mr * ai[j] + mi * ar[j];
        }
#pragma unroll
        for (int j = 0; j < 4; ++j) {
            pr[j] = __shfl_xor(lr[j], 1, 64);
            pi[j] = __shfl_xor(li[j], 1, 64);
        }
#pragma unroll
        for (int j = 0; j < 4; ++j) {
            // h=0: local(p*a) + partner(q*b);  h=1: partner(p*a) - local(q*b)
            ar[j] = h ? (pr[j] - lr[j]) : (lr[j] + pr[j]);
            ai[j] = h ? (pi[j] - li[j]) : (li[j] + pi[j]);
        }

        // ---- fused H+RX on qubit 1: pairs (j, j+2), thread-local
#pragma unroll
        for (int j = 0; j < 2; ++j) {
            float xr_ = p1r * ar[j]     - p1i * ai[j];
            float xi_ = p1r * ai[j]     + p1i * ar[j];
            float yr_ = q1r * ar[j + 2] - q1i * ai[j + 2];
            float yi_ = q1r * ai[j + 2] + q1i * ar[j + 2];
            ar[j]     = xr_ + yr_;  ai[j]     = xi_ + yi_;
            ar[j + 2] = xr_ - yr_;  ai[j + 2] = xi_ - yi_;
        }

        // ---- CNOT (q0 ctrl, q2 tgt): h==1 swaps j0<->j1, j2<->j3
        const int a = h ? 1 : 0, b = h ? 0 : 1, c = h ? 3 : 2, d = h ? 2 : 3;
        buf[par][2 * tid]     = make_float4(ar[a], ai[a], ar[b], ai[b]);
        buf[par][2 * tid + 1] = make_float4(ar[c], ai[c], ar[d], ai[d]);
        __syncthreads();

        // ---- block-contiguous nontemporal stores (unit stride, no L3 alloc)
        const long gbase = 2L * (long)(u - tid);  // block tile base in o4
        float4_n* __restrict__ dst = (float4_n*)(o4 + gbase);
        const float4_n* __restrict__ src = (const float4_n*)buf[par];
        const long lim = 2L * (long)N;
        if (gbase + tid < lim)
            __builtin_nontemporal_store(src[tid], &dst[tid]);
        if (gbase + tid + 256 < lim)
            __builtin_nontemporal_store(src[tid + 256], &dst[tid + 256]);

        // ---- rotate pipeline
        par ^= 1;
        u = un;
        fr = frn;
        fi = fin;
    }
}

extern "C" void kernel_launch(void* const* d_in, const int* in_sizes, int n_in,
                              void* d_out, int out_size, void* d_ws, size_t ws_size,
                              hipStream_t stream) {
    const float4* xr4  = (const float4*)d_in[0];
    const float4* xi4  = (const float4*)d_in[1];
    const float* theta = (const float*)d_in[2];
    float4* o4 = (float4*)d_out;

    int N = in_sizes[0] / 4;  // B*8 floats / 4 = 2B half-states
    int block = 256;
    int grid  = 2048;         // persistent: ~8 blocks/CU resident, one generation
    int stride = grid * block;
    int niters = (N + stride - 1) / stride;  // 8 for B = 2^21
    circuit_kernel<<<grid, block, 0, stream>>>(xr4, xi4, theta, o4, N, niters);
}